// Round 6
// baseline (204.747 us; speedup 1.0000x reference)
//
#include <hip/hip_runtime.h>
#include <hip/hip_bf16.h>

#define C_NUM 100000
#define D_EMB 512
#define N_BATCH 512
#define SCALE_F 30.0f
#define MARGIN_F 0.4f
#define H_F 0.333f
#define NTILES 1563          // ceil(100000/64)
#define GRID_MAIN 512        // persistent, 2 blocks/CU
#define KCH 128              // K elements per chunk
#define CHB (64 * KCH * 2)   // chunk buffer bytes = 16 KiB

typedef __attribute__((ext_vector_type(8))) short bf16x8;
typedef __attribute__((ext_vector_type(4))) short bf16x4;
typedef __attribute__((ext_vector_type(4))) float f32x4;
typedef __attribute__((ext_vector_type(16))) float f32x16;

static __device__ __forceinline__ short f2bf(float f) {
  __hip_bfloat16 h = __float2bfloat16(f);
  union { __hip_bfloat16 b; short s; } u;
  u.b = h;
  return u.s;
}

static __device__ __forceinline__ float sq4(f32x4 v) {
  return v[0]*v[0] + v[1]*v[1] + v[2]*v[2] + v[3]*v[3];
}

// ---------------------------------------------------------------------------
// Kernel 1: per-row L2 norm of embeddings; unit-normalized rows as bf16.
// ---------------------------------------------------------------------------
__global__ __launch_bounds__(64) void k_rownorm(const float* __restrict__ emb,
                                                short* __restrict__ Aunit,
                                                float* __restrict__ norms) {
  const int i = blockIdx.x;
  const int l = threadIdx.x;
  const f32x4* row = reinterpret_cast<const f32x4*>(emb + (size_t)i * D_EMB);
  f32x4 v0 = row[l];
  f32x4 v1 = row[l + 64];
  float ss = sq4(v0) + sq4(v1);
#pragma unroll
  for (int m = 1; m < 64; m <<= 1) ss += __shfl_xor(ss, m);
  float nrm = sqrtf(ss);
  float inv = 1.0f / nrm;
  bf16x4 o0, o1;
#pragma unroll
  for (int q = 0; q < 4; ++q) { o0[q] = f2bf(v0[q] * inv); o1[q] = f2bf(v1[q] * inv); }
  bf16x4* dst = reinterpret_cast<bf16x4*>(Aunit + (size_t)i * D_EMB);
  dst[l] = o0;
  dst[l + 64] = o1;
  if (l == 0) norms[i] = nrm;
}

// ---------------------------------------------------------------------------
// Kernel 2: batch mean / unbiased std -> adaptive margin per row.
// ---------------------------------------------------------------------------
__global__ __launch_bounds__(512) void k_stats(const float* __restrict__ norms,
                                               float* __restrict__ marg) {
  __shared__ float red[8];
  const int t = threadIdx.x;
  const int lane = t & 63, wid = t >> 6;
  float x = norms[t];
  float s = x;
#pragma unroll
  for (int m = 1; m < 64; m <<= 1) s += __shfl_xor(s, m);
  if (lane == 0) red[wid] = s;
  __syncthreads();
  float tot = 0.f;
#pragma unroll
  for (int q = 0; q < 8; ++q) tot += red[q];
  const float mean = tot / 512.f;
  __syncthreads();
  float d = x - mean;
  float s2 = d * d;
#pragma unroll
  for (int m = 1; m < 64; m <<= 1) s2 += __shfl_xor(s2, m);
  if (lane == 0) red[wid] = s2;
  __syncthreads();
  float tot2 = 0.f;
#pragma unroll
  for (int q = 0; q < 8; ++q) tot2 += red[q];
  const float stdv = sqrtf(tot2 / 511.f);   // ddof=1
  float msc = (x - mean) / (stdv + H_F);
  msc = fminf(1.f, fmaxf(-1.f, msc));
  marg[t] = MARGIN_F * (1.f + msc);
}

// ---------------------------------------------------------------------------
// Kernel 3: persistent pipelined main.
// Each block owns tiles {bid, bid+512, ...}. Tile = 64 classes x 512 K,
// split into 4 K-chunks of 128, double-buffered (2 x 16 KiB LDS).
// Phase g: [issue global loads chunk g+1] -> [compute chunk g: 32 MFMA] ->
// [cvt+ds_write chunk g+1, sumsq accumulate] -> [epilogue if last chunk] ->
// barrier. Weight streaming overlaps MFMA continuously (T14 issue-early).
// ---------------------------------------------------------------------------
__global__ __launch_bounds__(512, 4) void k_main(const short* __restrict__ Aunit,
                                                 const float* __restrict__ weight,
                                                 const int* __restrict__ labels,
                                                 const float* __restrict__ marg,
                                                 float* __restrict__ partial,
                                                 float* __restrict__ tlogit) {
  __shared__ alignas(16) short Bs[2][64 * KCH];   // 2 x 16 KiB
  __shared__ float winv[64];
  __shared__ int   lab_s[512];
  __shared__ float marg_s[512];

  const int tid = threadIdx.x;
  const int t0 = blockIdx.x;                 // first tile (GRID_MAIN < NTILES)

  // staging roles (fixed): 8 threads per class
  const int sc = tid >> 3;                   // class-in-tile 0..63
  const int sj = tid & 7;

  // compute roles
  const int wid = tid >> 6, lane = tid & 63;
  const int rbase = wid * 64;
  const int l31 = lane & 31, lhi = lane >> 5;
  const int swz = (l31 & 15) << 4;
  const short* arow0 = Aunit + (size_t)(rbase + l31) * D_EMB;
  const short* arow1 = Aunit + (size_t)(rbase + 32 + l31) * D_EMB;

  lab_s[tid] = labels[tid];
  marg_s[tid] = marg[tid];

  float ss = 0.f;
  // ---- prologue: stage (t0, chunk 0) into Bs[0] ----
  {
    const int gc = t0 * 64 + sc;
    const bool vn = gc < C_NUM;
    const float* wp = weight + ((size_t)gc << 9) + (sj << 2);
    f32x4 z = {0.f, 0.f, 0.f, 0.f};
    f32x4 s0 = vn ? *(const f32x4*)(wp)      : z;
    f32x4 s1 = vn ? *(const f32x4*)(wp + 32) : z;
    f32x4 s2 = vn ? *(const f32x4*)(wp + 64) : z;
    f32x4 s3 = vn ? *(const f32x4*)(wp + 96) : z;
    ss = sq4(s0) + sq4(s1) + sq4(s2) + sq4(s3);
    char* nb = (char*)(&Bs[0][0]);
#pragma unroll
    for (int q = 0; q < 4; ++q) {
      f32x4 v = (q == 0) ? s0 : (q == 1) ? s1 : (q == 2) ? s2 : s3;
      bf16x4 b;
#pragma unroll
      for (int e = 0; e < 4; ++e) b[e] = f2bf(v[e]);
      const int byte = (sc * 256 + (q * 8 + sj) * 8) ^ swz;
      *reinterpret_cast<bf16x4*>(nb + byte) = b;
    }
  }
  __syncthreads();

  int cur = 0;
  for (int t = t0; t < NTILES; t += GRID_MAIN) {
    f32x16 acc00, acc01, acc10, acc11;
#pragma unroll
    for (int q = 0; q < 16; ++q) { acc00[q] = 0.f; acc01[q] = 0.f; acc10[q] = 0.f; acc11[q] = 0.f; }

    for (int c = 0; c < 4; ++c) {
      // ---- next chunk coords ----
      int nt = t, nc = c + 1;
      if (nc == 4) { nc = 0; nt = t + GRID_MAIN; }
      const bool hasNext = nt < NTILES;

      // ---- issue next-chunk loads (consumed after compute) ----
      f32x4 s0, s1, s2, s3;
      {
        f32x4 z = {0.f, 0.f, 0.f, 0.f};
        const int gcn = nt * 64 + sc;
        const bool vn = hasNext && gcn < C_NUM;
        const float* wp = weight + ((size_t)gcn << 9) + (nc << 7) + (sj << 2);
        s0 = vn ? *(const f32x4*)(wp)      : z;
        s1 = vn ? *(const f32x4*)(wp + 32) : z;
        s2 = vn ? *(const f32x4*)(wp + 64) : z;
        s3 = vn ? *(const f32x4*)(wp + 96) : z;
      }

      // ---- compute chunk c from Bs[cur] ----
      {
        const char* bufB = (const char*)(&Bs[0][0]) + cur * CHB;
        const int cb = c << 7;      // chunk K base (elements)
#pragma unroll
        for (int kks = 0; kks < 8; ++kks) {
          const int kc = kks * 16 + lhi * 8;        // k within chunk
          bf16x8 a0 = *reinterpret_cast<const bf16x8*>(arow0 + cb + kc);
          bf16x8 a1 = *reinterpret_cast<const bf16x8*>(arow1 + cb + kc);
          bf16x8 b0 = *reinterpret_cast<const bf16x8*>(bufB + ((l31 * 256 + kc * 2) ^ swz));
          bf16x8 b1 = *reinterpret_cast<const bf16x8*>(bufB + (((l31 + 32) * 256 + kc * 2) ^ swz));
          acc00 = __builtin_amdgcn_mfma_f32_32x32x16_bf16(a0, b0, acc00, 0, 0, 0);
          acc01 = __builtin_amdgcn_mfma_f32_32x32x16_bf16(a0, b1, acc01, 0, 0, 0);
          acc10 = __builtin_amdgcn_mfma_f32_32x32x16_bf16(a1, b0, acc10, 0, 0, 0);
          acc11 = __builtin_amdgcn_mfma_f32_32x32x16_bf16(a1, b1, acc11, 0, 0, 0);
        }
      }

      // ---- write next chunk to the other buffer, sumsq bookkeeping ----
      if (hasNext) {
        if (nc == 0) ss = 0.f;
        ss += sq4(s0) + sq4(s1) + sq4(s2) + sq4(s3);
        char* nb = (char*)(&Bs[0][0]) + (cur ^ 1) * CHB;
#pragma unroll
        for (int q = 0; q < 4; ++q) {
          f32x4 v = (q == 0) ? s0 : (q == 1) ? s1 : (q == 2) ? s2 : s3;
          bf16x4 b;
#pragma unroll
          for (int e = 0; e < 4; ++e) b[e] = f2bf(v[e]);
          const int byte = (sc * 256 + (q * 8 + sj) * 8) ^ ((sc & 15) << 4);
          *reinterpret_cast<bf16x4*>(nb + byte) = b;
        }
        if (nc == 3) {       // tile nt(==t)'s sumsq complete -> winv for epilogue next phase
          float s = ss;
          s += __shfl_xor(s, 1);
          s += __shfl_xor(s, 2);
          s += __shfl_xor(s, 4);
          if (sj == 0) winv[sc] = (s > 0.f) ? rsqrtf(s) : 0.f;
        }
      }

      // ---- epilogue on last chunk of tile t ----
      if (c == 3) {
        const float wv0 = winv[l31];
        const float wv1 = winv[32 + l31];
        const int gcc0 = t * 64 + l31;
        const int gcc1 = gcc0 + 32;
        const bool v0ok = gcc0 < C_NUM;
        const bool v1ok = gcc1 < C_NUM;
#pragma unroll
        for (int mi = 0; mi < 2; ++mi) {
#pragma unroll
          for (int r = 0; r < 16; ++r) {
            const int rowf = (r & 3) + 8 * (r >> 2) + 4 * lhi;
            const int R = rbase + mi * 32 + rowf;
            const int lab = lab_s[R];
            float c0v = (mi ? acc10[r] : acc00[r]) * wv0;
            float c1v = (mi ? acc11[r] : acc01[r]) * wv1;
            float lg0 = SCALE_F * c0v;
            float lg1 = SCALE_F * c1v;
            if (lab == gcc0) {
              float ct = fminf(1.f, fmaxf(-1.f, c0v));
              float lt = SCALE_F * cosf(acosf(ct) + marg_s[R]);
              lg0 = lt; tlogit[R] = lt;
            }
            if (lab == gcc1) {
              float ct = fminf(1.f, fmaxf(-1.f, c1v));
              float lt = SCALE_F * cosf(acosf(ct) + marg_s[R]);
              lg1 = lt; tlogit[R] = lt;
            }
            float v = (v0ok ? __expf(lg0) : 0.f) + (v1ok ? __expf(lg1) : 0.f);
            v += __shfl_xor(v, 1);
            v += __shfl_xor(v, 2);
            v += __shfl_xor(v, 4);
            v += __shfl_xor(v, 8);
            v += __shfl_xor(v, 16);
            if (l31 == 0) partial[(size_t)t * N_BATCH + R] = v;
          }
        }
      }

      __syncthreads();
      cur ^= 1;
    }
  }
}

// ---------------------------------------------------------------------------
// Kernel 4: per-row reduce over tiles: term[r] = log(sum_t partial[t][r]) - tlogit[r]
// ---------------------------------------------------------------------------
__global__ __launch_bounds__(64) void k_reduce(const float* __restrict__ partial,
                                               const float* __restrict__ tlogit,
                                               float* __restrict__ term) {
  const int r = blockIdx.x;
  const int l = threadIdx.x;
  float s = 0.f;
  for (int b = l; b < NTILES; b += 64)
    s += partial[(size_t)b * N_BATCH + r];
#pragma unroll
  for (int m = 1; m < 64; m <<= 1) s += __shfl_xor(s, m);
  if (l == 0) term[r] = logf(s) - tlogit[r];
}

// ---------------------------------------------------------------------------
// Kernel 5: loss = mean(term)
// ---------------------------------------------------------------------------
__global__ __launch_bounds__(512) void k_final(const float* __restrict__ term,
                                               float* __restrict__ out) {
  __shared__ float red[8];
  const int t = threadIdx.x;
  const int lane = t & 63, wid = t >> 6;
  float v = term[t];
#pragma unroll
  for (int m = 1; m < 64; m <<= 1) v += __shfl_xor(v, m);
  if (lane == 0) red[wid] = v;
  __syncthreads();
  if (t == 0) {
    float tot = 0.f;
#pragma unroll
    for (int q = 0; q < 8; ++q) tot += red[q];
    out[0] = tot / 512.f;
  }
}

extern "C" void kernel_launch(void* const* d_in, const int* in_sizes, int n_in,
                              void* d_out, int out_size, void* d_ws, size_t ws_size,
                              hipStream_t stream) {
  const float* emb    = (const float*)d_in[0];
  const int*   labels = (const int*)d_in[1];
  const float* weight = (const float*)d_in[2];
  float* out = (float*)d_out;

  char* ws = (char*)d_ws;
  short* Aunit   = (short*)ws;                        // 512*512*2 = 524288 B
  float* norms   = (float*)(ws + 524288);             // 2 KiB
  float* marg    = (float*)(ws + 524288 + 2048);      // 2 KiB
  float* tlog    = (float*)(ws + 524288 + 4096);      // 2 KiB
  float* term    = (float*)(ws + 524288 + 6144);      // 2 KiB
  float* partial = (float*)(ws + 524288 + 8192);      // 1563*512*4 = 3201024 B

  k_rownorm<<<N_BATCH, 64, 0, stream>>>(emb, Aunit, norms);
  k_stats<<<1, 512, 0, stream>>>(norms, marg);
  k_main<<<GRID_MAIN, 512, 0, stream>>>(Aunit, weight, labels, marg, partial, tlog);
  k_reduce<<<N_BATCH, 64, 0, stream>>>(partial, tlog, term);
  k_final<<<1, 512, 0, stream>>>(term, out);
}